// Round 6
// baseline (746.090 us; speedup 1.0000x reference)
//
#include <hip/hip_runtime.h>
#include <math.h>
#include <stdint.h>

#define B_ 32
#define N_ 1024
#define D_ 256
#define K_ 8
#define CAND 12

typedef unsigned short u16;
typedef __attribute__((ext_vector_type(8))) short s16x8;   // 8 bf16 (4 VGPRs)
typedef __attribute__((ext_vector_type(16))) float f32x16; // 32x32 accumulator

__device__ inline u16 f2bf(float f) {               // RNE float->bf16 bits
    uint32_t u = __float_as_uint(f);
    return (u16)((u + 0x7fffu + ((u >> 16) & 1u)) >> 16);
}
__device__ inline float bf2f(u16 h) { return __uint_as_float(((uint32_t)h) << 16); }

// ------------- Kernel 1: fp64 inverse norms + normalized bf16 hi/lo -------------
__global__ __launch_bounds__(256) void prep_kernel(const float* __restrict__ tok,
                                                   double* __restrict__ invn,
                                                   u16* __restrict__ xhi,
                                                   u16* __restrict__ xlo) {
    const int tid = threadIdx.x;
    const int wave = tid >> 6, lane = tid & 63;
    const int row = blockIdx.x * 4 + wave;          // 32768 rows
    const float4 v = *reinterpret_cast<const float4*>(tok + (size_t)row * D_ + lane * 4);
    double s = (double)v.x * v.x + (double)v.y * v.y +
               (double)v.z * v.z + (double)v.w * v.w;
    #pragma unroll
    for (int off = 32; off > 0; off >>= 1) s += __shfl_xor(s, off, 64);
    const double inv = 1.0 / (sqrt(s) + 1e-8);
    if (lane == 0) invn[row] = inv;
    const float x0 = (float)(v.x * inv), x1 = (float)(v.y * inv),
                x2 = (float)(v.z * inv), x3 = (float)(v.w * inv);
    ushort4 h, l;
    h.x = f2bf(x0); l.x = f2bf(x0 - bf2f(h.x));
    h.y = f2bf(x1); l.y = f2bf(x1 - bf2f(h.y));
    h.z = f2bf(x2); l.z = f2bf(x2 - bf2f(h.z));
    h.w = f2bf(x3); l.w = f2bf(x3 - bf2f(h.w));
    *reinterpret_cast<ushort4*>(xhi + (size_t)row * D_ + lane * 4) = h;
    *reinterpret_cast<ushort4*>(xlo + (size_t)row * D_ + lane * 4) = l;
}

// ------------- Kernel 2: MFMA sim + fused top-12 + fp64 rescore -------------
// grid (32 batches, 16 strips): linear block id % 8 == batch % 8 -> all strips
// of a batch co-locate on one XCD, making its 1 MB B-data L2-resident.
// Staging is register-prefetched one stage ahead (R5 was latency-bound on the
// barrier-locked L2/L3 loads: 8K cyc/stage with only ~600 cyc of real work).
#define AL_OFF  0
#define BH_OFF  8192
#define BL_OFF  16384
#define SIM_OFF 24576       // float [64][67]
#define SIM_P   67
#define LDS_SZ  41728

__global__ __launch_bounds__(256, 2) void sim_topk_kernel(const u16* __restrict__ Xhi,
                                                          const u16* __restrict__ Xlo,
                                                          const float* __restrict__ tok,
                                                          const double* __restrict__ invn,
                                                          int* __restrict__ topk) {
    __shared__ __align__(16) char smem[LDS_SZ];
    float*  SimT = (float*)(smem + SIM_OFF);
    float*  pv   = (float*)(smem);             // aliases (post-loop only)
    int*    pi   = (int*)(smem + 12288);
    int*    mj   = (int*)(smem + 24576);
    double* dv   = (double*)(smem + 27648);

    const int b  = blockIdx.x;                  // batch on x for XCD locality
    const int i0 = blockIdx.y * 64;
    const int tid = threadIdx.x;
    const int w = tid >> 6, lane = tid & 63;
    const int mq = w >> 1, nq = w & 1;          // 2x2 wave grid of 32x32 tiles
    const int half = lane >> 5;

    const u16* XhiB = Xhi + (size_t)b * N_ * D_;
    const u16* XloB = Xlo + (size_t)b * N_ * D_;

    const int ra = mq * 32 + (lane & 31);       // A row in strip
    const int rb = nq * 32 + (lane & 31);       // B row in j-tile

    // staging indices (2 chunks per thread per tile)
    const int qr0 = tid >> 3,        qc0 = tid & 7;
    const int qr1 = (256 + tid) >> 3, qc1 = tid & 7;   // = qr0+32, same qc

    // ---- prefetch stage 0 (jt=0, kc=0) ----
    float4 cur[6], nxt[6];
    cur[0] = *(const float4*)(XloB + (size_t)(i0 + qr0) * D_ + qc0 * 8);
    cur[1] = *(const float4*)(XloB + (size_t)(i0 + qr1) * D_ + qc1 * 8);
    cur[2] = *(const float4*)(XhiB + (size_t)(0  + qr0) * D_ + qc0 * 8);
    cur[3] = *(const float4*)(XhiB + (size_t)(0  + qr1) * D_ + qc1 * 8);
    cur[4] = *(const float4*)(XloB + (size_t)(0  + qr0) * D_ + qc0 * 8);
    cur[5] = *(const float4*)(XloB + (size_t)(0  + qr1) * D_ + qc1 * 8);

    // ---- A-hi fragments for full K in registers (64 VGPRs) ----
    s16x8 afh[4][4];
    {
        const u16* ar = XhiB + (size_t)(i0 + ra) * D_ + half * 8;
        #pragma unroll
        for (int kc = 0; kc < 4; ++kc)
            #pragma unroll
            for (int ks = 0; ks < 4; ++ks)
                afh[kc][ks] = *(const s16x8*)(ar + kc * 64 + ks * 16);
    }

    const int sr = tid & 63, sq = tid >> 6;     // scan: 4 threads/row, 16 cols each
    const int gi_scan = i0 + sr;
    const int sw0 = (qc0 ^ (qr0 & 7)) * 16;     // LDS write swizzle offsets
    const int sw1 = (qc1 ^ (qr1 & 7)) * 16;

    float vals[CAND]; int idxs[CAND];
    #pragma unroll
    for (int c = 0; c < CAND; ++c) { vals[c] = -INFINITY; idxs[c] = -1; }

    for (int jt = 0; jt < 16; ++jt) {
        f32x16 a1, a2, a3;                      // 3 independent MFMA chains
        #pragma unroll
        for (int c = 0; c < 16; ++c) { a1[c] = 0.f; a2[c] = 0.f; a3[c] = 0.f; }

        #pragma unroll
        for (int kc = 0; kc < 4; ++kc) {
            __syncthreads();                    // tiles free for overwrite
            // write the prefetched stage
            *(float4*)(smem + AL_OFF + qr0 * 128 + sw0) = cur[0];
            *(float4*)(smem + AL_OFF + qr1 * 128 + sw1) = cur[1];
            *(float4*)(smem + BH_OFF + qr0 * 128 + sw0) = cur[2];
            *(float4*)(smem + BH_OFF + qr1 * 128 + sw1) = cur[3];
            *(float4*)(smem + BL_OFF + qr0 * 128 + sw0) = cur[4];
            *(float4*)(smem + BL_OFF + qr1 * 128 + sw1) = cur[5];
            // prefetch next stage (issued now, consumed after next barrier+MFMA)
            const int sn = jt * 4 + kc + 1;
            if (sn < 64) {
                const int j0n = (sn >> 2) * 64;
                const int kn  = (sn & 3) * 64;
                nxt[0] = *(const float4*)(XloB + (size_t)(i0  + qr0) * D_ + kn + qc0 * 8);
                nxt[1] = *(const float4*)(XloB + (size_t)(i0  + qr1) * D_ + kn + qc1 * 8);
                nxt[2] = *(const float4*)(XhiB + (size_t)(j0n + qr0) * D_ + kn + qc0 * 8);
                nxt[3] = *(const float4*)(XhiB + (size_t)(j0n + qr1) * D_ + kn + qc1 * 8);
                nxt[4] = *(const float4*)(XloB + (size_t)(j0n + qr0) * D_ + kn + qc0 * 8);
                nxt[5] = *(const float4*)(XloB + (size_t)(j0n + qr1) * D_ + kn + qc1 * 8);
            }
            __syncthreads();
            #pragma unroll
            for (int ks = 0; ks < 4; ++ks) {
                const int lc = ks * 2 + half;   // logical 16B chunk in 128B row
                const s16x8 al = *(const s16x8*)(smem + AL_OFF + ra * 128 + ((lc ^ (ra & 7)) * 16));
                const s16x8 bh = *(const s16x8*)(smem + BH_OFF + rb * 128 + ((lc ^ (rb & 7)) * 16));
                const s16x8 bl = *(const s16x8*)(smem + BL_OFF + rb * 128 + ((lc ^ (rb & 7)) * 16));
                a1 = __builtin_amdgcn_mfma_f32_32x32x16_bf16(afh[kc][ks], bh, a1, 0, 0, 0);
                a2 = __builtin_amdgcn_mfma_f32_32x32x16_bf16(afh[kc][ks], bl, a2, 0, 0, 0);
                a3 = __builtin_amdgcn_mfma_f32_32x32x16_bf16(al,          bh, a3, 0, 0, 0);
            }
            #pragma unroll
            for (int u = 0; u < 6; ++u) cur[u] = nxt[u];
        }

        // C/D layout: col=lane&31, row=(reg&3)+8*(reg>>2)+4*(lane>>5)  [m74/m101]
        {
            const int col = nq * 32 + (lane & 31);
            const int rbase = mq * 32 + 4 * half;
            #pragma unroll
            for (int reg = 0; reg < 16; ++reg)
                SimT[(rbase + (reg & 3) + 8 * (reg >> 2)) * SIM_P + col] =
                    a1[reg] + a2[reg] + a3[reg];
        }
        __syncthreads();

        // per-row candidate scan
        const int j0 = jt * 64;
        #pragma unroll 4
        for (int c = 0; c < 16; ++c) {
            const int jl = sq * 16 + c;
            const int gj = j0 + jl;
            const float v = SimT[sr * SIM_P + jl];
            if (gj != gi_scan && v > vals[CAND - 1]) {
                float cv = v; int ci = gj;
                #pragma unroll
                for (int cc = 0; cc < CAND; ++cc) {
                    if (cv > vals[cc]) {
                        const float tv = vals[cc]; vals[cc] = cv; cv = tv;
                        const int   ti = idxs[cc]; idxs[cc] = ci; ci = ti;
                    }
                }
            }
        }
        // next jt's first barrier protects SimT before rewrite
    }

    __syncthreads();                            // tiles dead -> alias pv/pi
    #pragma unroll
    for (int c = 0; c < CAND; ++c) { pv[tid * CAND + c] = vals[c]; pi[tid * CAND + c] = idxs[c]; }
    __syncthreads();

    // 4-way merge of sorted partial lists -> top-12 per row
    if (tid < 64) {
        int p0 = 0, p1 = 0, p2 = 0, p3 = 0;
        #pragma unroll
        for (int o = 0; o < CAND; ++o) {
            const float v0 = pv[(tid      ) * CAND + p0];
            const float v1 = pv[(tid +  64) * CAND + p1];
            const float v2 = pv[(tid + 128) * CAND + p2];
            const float v3 = pv[(tid + 192) * CAND + p3];
            int bg = 0; float bv = v0;
            if (v1 > bv) { bv = v1; bg = 1; }
            if (v2 > bv) { bv = v2; bg = 2; }
            if (v3 > bv) { bv = v3; bg = 3; }
            const int pp = (bg == 0) ? p0 : (bg == 1) ? p1 : (bg == 2) ? p2 : p3;
            mj[tid * CAND + o] = pi[(tid + 64 * bg) * CAND + pp];
            p0 += (bg == 0); p1 += (bg == 1); p2 += (bg == 2); p3 += (bg == 3);
        }
    }
    __syncthreads();

    // fp64 rescore, parallel over 3 groups of 4 candidates
    const float*  tokB = tok  + (size_t)b * N_ * D_;
    const double* invB = invn + b * N_;
    if (tid < 192) {
        const int r = tid & 63, g = tid >> 6;
        const int gi = i0 + r;
        const float* qi = tokB + (size_t)gi * D_;
        const double di = invB[gi];
        #pragma unroll 1
        for (int cc = 0; cc < 4; ++cc) {
            const int c = g * 4 + cc;
            const int j = mj[r * CAND + c];
            const float* qj = tokB + (size_t)j * D_;
            double s = 0.0;
            for (int d = 0; d < D_; d += 4) {
                const float4 x = *reinterpret_cast<const float4*>(qi + d);
                const float4 y = *reinterpret_cast<const float4*>(qj + d);
                s += (double)x.x * y.x + (double)x.y * y.y +
                     (double)x.z * y.z + (double)x.w * y.w;
            }
            dv[r * CAND + c] = s * di * invB[j];
        }
    }
    __syncthreads();

    // exact top-8 by fp64 rank (ties -> lower index, matching lax.top_k)
    if (tid < 64) {
        const int out_base = (b * N_ + i0 + tid) * K_;
        #pragma unroll 1
        for (int c = 0; c < CAND; ++c) {
            const double dc = dv[tid * CAND + c]; const int jc = mj[tid * CAND + c];
            int rank = 0;
            #pragma unroll 1
            for (int c2 = 0; c2 < CAND; ++c2) {
                if (c2 == c) continue;
                const double d2 = dv[tid * CAND + c2]; const int j2 = mj[tid * CAND + c2];
                if (d2 > dc || (d2 == dc && j2 < jc)) ++rank;
            }
            if (rank < K_) topk[out_base + rank] = jc;
        }
    }
}

// ------------- Kernel 3: fused zero + mutual scatter, one wave per row -------------
__global__ __launch_bounds__(256) void out_kernel(const int* __restrict__ topk,
                                                  float* __restrict__ out) {
    const int w = threadIdx.x >> 6, lane = threadIdx.x & 63;
    const int row = blockIdx.x * 4 + w;         // b*1024 + i
    const int i = row & (N_ - 1);
    int jm = -1;
    if (lane < K_) {
        const int j = topk[row * K_ + lane];
        const int* tj = topk + ((row & ~(N_ - 1)) + j) * K_;
        bool m = false;
        #pragma unroll
        for (int u = 0; u < K_; ++u) m = m || (tj[u] == i);
        if (m) jm = j;
    }
    int js[K_];
    #pragma unroll
    for (int s = 0; s < K_; ++s) js[s] = __shfl(jm, s, 64);
    float* orow = out + (size_t)row * N_;
    #pragma unroll
    for (int q = 0; q < 4; ++q) {
        const int cbase = q * 256 + lane * 4;   // coalesced: wave covers 1KB
        float4 v = {0.f, 0.f, 0.f, 0.f};
        #pragma unroll
        for (int s = 0; s < K_; ++s) {
            const int d = js[s] - cbase;
            if (d == 0) v.x = 1.0f;
            else if (d == 1) v.y = 1.0f;
            else if (d == 2) v.z = 1.0f;
            else if (d == 3) v.w = 1.0f;
        }
        *reinterpret_cast<float4*>(orow + cbase) = v;
    }
}

extern "C" void kernel_launch(void* const* d_in, const int* in_sizes, int n_in,
                              void* d_out, int out_size, void* d_ws, size_t ws_size,
                              hipStream_t stream) {
    const float* tok = (const float*)d_in[0];
    float* out = (float*)d_out;
    double* invn = (double*)d_ws;                                  // 256 KB
    int* topk = (int*)((char*)d_ws + (size_t)B_ * N_ * sizeof(double)); // 1 MB
    // bf16 hi/lo scratch lives in d_out (32 MB of 128 MB) until out_kernel
    u16* xhi = (u16*)d_out;
    u16* xlo = xhi + (size_t)B_ * N_ * D_;

    prep_kernel<<<dim3(B_ * N_ / 4), 256, 0, stream>>>(tok, invn, xhi, xlo);
    sim_topk_kernel<<<dim3(B_, 16), 256, 0, stream>>>(xhi, xlo, tok, invn, topk);
    out_kernel<<<dim3(B_ * N_ / 4), 256, 0, stream>>>(topk, out);
}

// Round 7
// 721.592 us; speedup vs baseline: 1.0340x; 1.0340x over previous
//
#include <hip/hip_runtime.h>
#include <math.h>
#include <stdint.h>

#define B_ 32
#define N_ 1024
#define D_ 256
#define D2 512              // concat(hi,lo) along K
#define K_ 8
#define CAND 12

typedef unsigned short u16;
typedef __attribute__((ext_vector_type(8))) short s16x8;   // 8 bf16 (4 VGPRs)
typedef __attribute__((ext_vector_type(16))) float f32x16; // 32x32 accumulator

__device__ inline u16 f2bf(float f) {               // RNE float->bf16 bits
    uint32_t u = __float_as_uint(f);
    return (u16)((u + 0x7fffu + ((u >> 16) & 1u)) >> 16);
}
__device__ inline float bf2f(u16 h) { return __uint_as_float(((uint32_t)h) << 16); }

// ------- Kernel 1: fp64 inverse norms + normalized bf16 hi|lo concat rows -------
__global__ __launch_bounds__(256) void prep_kernel(const float* __restrict__ tok,
                                                   double* __restrict__ invn,
                                                   u16* __restrict__ X2) {
    const int tid = threadIdx.x;
    const int wave = tid >> 6, lane = tid & 63;
    const int row = blockIdx.x * 4 + wave;          // 32768 rows
    const float4 v = *reinterpret_cast<const float4*>(tok + (size_t)row * D_ + lane * 4);
    double s = (double)v.x * v.x + (double)v.y * v.y +
               (double)v.z * v.z + (double)v.w * v.w;
    #pragma unroll
    for (int off = 32; off > 0; off >>= 1) s += __shfl_xor(s, off, 64);
    const double inv = 1.0 / (sqrt(s) + 1e-8);
    if (lane == 0) invn[row] = inv;
    const float x0 = (float)(v.x * inv), x1 = (float)(v.y * inv),
                x2 = (float)(v.z * inv), x3 = (float)(v.w * inv);
    ushort4 h, l;
    h.x = f2bf(x0); l.x = f2bf(x0 - bf2f(h.x));
    h.y = f2bf(x1); l.y = f2bf(x1 - bf2f(h.y));
    h.z = f2bf(x2); l.z = f2bf(x2 - bf2f(h.z));
    h.w = f2bf(x3); l.w = f2bf(x3 - bf2f(h.w));
    *reinterpret_cast<ushort4*>(X2 + (size_t)row * D2 + lane * 4) = h;
    *reinterpret_cast<ushort4*>(X2 + (size_t)row * D2 + 256 + lane * 4) = l;
}

// ------- Kernel 2: bf16 GEMM Sim = X2 . X2^T (per batch), 128x128 tile -------
// grid (8 i-tiles, 8 j-tiles, 16 batches). R5-verified XOR-swizzled staging +
// 32x32x16 fragment/CD layouts. LDS 32 KB. Single MFMA dependency set (2x2/wave).
__global__ __launch_bounds__(256, 2) void gemm_kernel(const u16* __restrict__ X2c,
                                                      float* __restrict__ Sim) {
    __shared__ __align__(16) char smem[32768];     // As 16 KB | Bs 16 KB
    char* As = smem;
    char* Bs = smem + 16384;

    const int bz = blockIdx.z;
    const int i0 = blockIdx.x * 128, j0 = blockIdx.y * 128;
    const int tid = threadIdx.x;
    const int w = tid >> 6, lane = tid & 63;
    const int wm = w >> 1, wn = w & 1;              // 2x2 waves over 128x128
    const int half = lane >> 5;

    const u16* Xb = X2c + (size_t)bz * N_ * D2;

    const int qr = tid >> 3, qc = tid & 7;          // staging: row, 16B chunk
    const int sw = (qc ^ (qr & 7)) * 16;

    const int ra0 = wm * 64 + (lane & 31), ra1 = ra0 + 32;
    const int rb0 = wn * 64 + (lane & 31), rb1 = rb0 + 32;

    f32x16 acc[2][2];
    #pragma unroll
    for (int si = 0; si < 2; ++si)
        #pragma unroll
        for (int sj = 0; sj < 2; ++sj)
            #pragma unroll
            for (int c = 0; c < 16; ++c) acc[si][sj][c] = 0.f;

    for (int kc = 0; kc < 8; ++kc) {                // K = 512, BK = 64
        const int k0 = kc * 64;
        __syncthreads();
        {   // stage A/B tiles: 4+4 coalesced float4 per thread, swizzled writes
            float4 sa[4], sb[4];
            #pragma unroll
            for (int u = 0; u < 4; ++u) {
                const int r = u * 32 + qr;
                sa[u] = *(const float4*)(Xb + (size_t)(i0 + r) * D2 + k0 + qc * 8);
                sb[u] = *(const float4*)(Xb + (size_t)(j0 + r) * D2 + k0 + qc * 8);
            }
            #pragma unroll
            for (int u = 0; u < 4; ++u) {
                const int r = u * 32 + qr;
                *(float4*)(As + r * 128 + sw) = sa[u];
                *(float4*)(Bs + r * 128 + sw) = sb[u];
            }
        }
        __syncthreads();
        #pragma unroll
        for (int ks = 0; ks < 4; ++ks) {
            const int lc = ks * 2 + half;           // logical 16B chunk
            const s16x8 a0 = *(const s16x8*)(As + ra0 * 128 + ((lc ^ (ra0 & 7)) * 16));
            const s16x8 a1 = *(const s16x8*)(As + ra1 * 128 + ((lc ^ (ra1 & 7)) * 16));
            const s16x8 b0 = *(const s16x8*)(Bs + rb0 * 128 + ((lc ^ (rb0 & 7)) * 16));
            const s16x8 b1 = *(const s16x8*)(Bs + rb1 * 128 + ((lc ^ (rb1 & 7)) * 16));
            acc[0][0] = __builtin_amdgcn_mfma_f32_32x32x16_bf16(a0, b0, acc[0][0], 0, 0, 0);
            acc[0][1] = __builtin_amdgcn_mfma_f32_32x32x16_bf16(a0, b1, acc[0][1], 0, 0, 0);
            acc[1][0] = __builtin_amdgcn_mfma_f32_32x32x16_bf16(a1, b0, acc[1][0], 0, 0, 0);
            acc[1][1] = __builtin_amdgcn_mfma_f32_32x32x16_bf16(a1, b1, acc[1][1], 0, 0, 0);
        }
    }

    // C/D: col=lane&31, row=(reg&3)+8*(reg>>2)+4*(lane>>5)  [R2..R5-verified]
    float* Simb = Sim + (size_t)bz * N_ * N_;
    #pragma unroll
    for (int si = 0; si < 2; ++si)
        #pragma unroll
        for (int sj = 0; sj < 2; ++sj) {
            const int cb = j0 + wn * 64 + sj * 32 + (lane & 31);
            const int rb = i0 + wm * 64 + si * 32 + 4 * half;
            #pragma unroll
            for (int reg = 0; reg < 16; ++reg)
                Simb[(size_t)(rb + (reg & 3) + 8 * (reg >> 2)) * N_ + cb] = acc[si][sj][reg];
        }
}

// ------- Kernel 3: scan Sim rows -> top-12 -> fp64 rescore -> topk -------
// grid (16 strips, 16 local batches). 4 threads/row, register-prefetched reads.
__global__ __launch_bounds__(256, 2) void scan_kernel(const float* __restrict__ Sim,
                                                      const float* __restrict__ tok,
                                                      const double* __restrict__ invn,
                                                      int* __restrict__ topk,
                                                      int batch_base) {
    __shared__ __align__(16) char smem[33792];
    float*  pv = (float*)(smem);
    int*    pi = (int*)(smem + 12288);
    int*    mj = (int*)(smem + 24576);
    double* dv = (double*)(smem + 27648);

    const int bl = blockIdx.y;                      // local batch
    const int b  = batch_base + bl;
    const int i0 = blockIdx.x * 64;
    const int tid = threadIdx.x;
    const int sr = tid & 63, sq = tid >> 6;         // row, col-quarter
    const int gi = i0 + sr;

    const float* base = Sim + (size_t)bl * N_ * N_ + (size_t)gi * N_ + sq * 16;

    float vals[CAND]; int idxs[CAND];
    #pragma unroll
    for (int c = 0; c < CAND; ++c) { vals[c] = -INFINITY; idxs[c] = -1; }

    float4 cur[4], nxt[4];
    #pragma unroll
    for (int u = 0; u < 4; ++u) cur[u] = *(const float4*)(base + u * 4);

    #pragma unroll 1
    for (int jt = 0; jt < 16; ++jt) {
        if (jt < 15) {
            #pragma unroll
            for (int u = 0; u < 4; ++u)
                nxt[u] = *(const float4*)(base + (jt + 1) * 64 + u * 4);
        }
        const int cb0 = jt * 64 + sq * 16;          // global col of cur[0].x
        float vbuf[16];
        #pragma unroll
        for (int u = 0; u < 4; ++u) {
            vbuf[u * 4 + 0] = cur[u].x; vbuf[u * 4 + 1] = cur[u].y;
            vbuf[u * 4 + 2] = cur[u].z; vbuf[u * 4 + 3] = cur[u].w;
        }
        #pragma unroll 4
        for (int c = 0; c < 16; ++c) {
            const int gj = cb0 + c;
            const float v = vbuf[c];
            if (gj != gi && v > vals[CAND - 1]) {
                float cv = v; int ci = gj;
                #pragma unroll
                for (int cc = 0; cc < CAND; ++cc) {
                    if (cv > vals[cc]) {
                        const float tv = vals[cc]; vals[cc] = cv; cv = tv;
                        const int   ti = idxs[cc]; idxs[cc] = ci; ci = ti;
                    }
                }
            }
        }
        #pragma unroll
        for (int u = 0; u < 4; ++u) cur[u] = nxt[u];
    }

    #pragma unroll
    for (int c = 0; c < CAND; ++c) { pv[tid * CAND + c] = vals[c]; pi[tid * CAND + c] = idxs[c]; }
    __syncthreads();

    // 4-way merge of sorted partial lists -> top-12 per row
    if (tid < 64) {
        int p0 = 0, p1 = 0, p2 = 0, p3 = 0;
        #pragma unroll
        for (int o = 0; o < CAND; ++o) {
            const float v0 = pv[(tid      ) * CAND + p0];
            const float v1 = pv[(tid +  64) * CAND + p1];
            const float v2 = pv[(tid + 128) * CAND + p2];
            const float v3 = pv[(tid + 192) * CAND + p3];
            int bg = 0; float bv = v0;
            if (v1 > bv) { bv = v1; bg = 1; }
            if (v2 > bv) { bv = v2; bg = 2; }
            if (v3 > bv) { bv = v3; bg = 3; }
            const int pp = (bg == 0) ? p0 : (bg == 1) ? p1 : (bg == 2) ? p2 : p3;
            mj[tid * CAND + o] = pi[(tid + 64 * bg) * CAND + pp];
            p0 += (bg == 0); p1 += (bg == 1); p2 += (bg == 2); p3 += (bg == 3);
        }
    }
    __syncthreads();

    // fp64 rescore, parallel over 3 groups of 4 candidates
    const float*  tokB = tok  + (size_t)b * N_ * D_;
    const double* invB = invn + b * N_;
    if (tid < 192) {
        const int r = tid & 63, g = tid >> 6;
        const int gr = i0 + r;
        const float* qi = tokB + (size_t)gr * D_;
        const double di = invB[gr];
        #pragma unroll 1
        for (int cc = 0; cc < 4; ++cc) {
            const int c = g * 4 + cc;
            const int j = mj[r * CAND + c];
            const float* qj = tokB + (size_t)j * D_;
            double s = 0.0;
            for (int d = 0; d < D_; d += 4) {
                const float4 x = *reinterpret_cast<const float4*>(qi + d);
                const float4 y = *reinterpret_cast<const float4*>(qj + d);
                s += (double)x.x * y.x + (double)x.y * y.y +
                     (double)x.z * y.z + (double)x.w * y.w;
            }
            dv[r * CAND + c] = s * di * invB[j];
        }
    }
    __syncthreads();

    // exact top-8 by fp64 rank (ties -> lower index, matching lax.top_k)
    if (tid < 64) {
        const int out_base = (b * N_ + i0 + tid) * K_;
        #pragma unroll 1
        for (int c = 0; c < CAND; ++c) {
            const double dc = dv[tid * CAND + c]; const int jc = mj[tid * CAND + c];
            int rank = 0;
            #pragma unroll 1
            for (int c2 = 0; c2 < CAND; ++c2) {
                if (c2 == c) continue;
                const double d2 = dv[tid * CAND + c2]; const int j2 = mj[tid * CAND + c2];
                if (d2 > dc || (d2 == dc && j2 < jc)) ++rank;
            }
            if (rank < K_) topk[out_base + rank] = jc;
        }
    }
}

// ------- Kernel 4: fused zero + mutual scatter, one wave per row -------
__global__ __launch_bounds__(256) void out_kernel(const int* __restrict__ topk,
                                                  float* __restrict__ out) {
    const int w = threadIdx.x >> 6, lane = threadIdx.x & 63;
    const int row = blockIdx.x * 4 + w;             // b*1024 + i
    const int i = row & (N_ - 1);
    int jm = -1;
    if (lane < K_) {
        const int j = topk[row * K_ + lane];
        const int* tj = topk + ((row & ~(N_ - 1)) + j) * K_;
        bool m = false;
        #pragma unroll
        for (int u = 0; u < K_; ++u) m = m || (tj[u] == i);
        if (m) jm = j;
    }
    int js[K_];
    #pragma unroll
    for (int s = 0; s < K_; ++s) js[s] = __shfl(jm, s, 64);
    float* orow = out + (size_t)row * N_;
    #pragma unroll
    for (int q = 0; q < 4; ++q) {
        const int cbase = q * 256 + lane * 4;       // coalesced: wave covers 1KB
        float4 v = {0.f, 0.f, 0.f, 0.f};
        #pragma unroll
        for (int s = 0; s < K_; ++s) {
            const int d = js[s] - cbase;
            if (d == 0) v.x = 1.0f;
            else if (d == 1) v.y = 1.0f;
            else if (d == 2) v.z = 1.0f;
            else if (d == 3) v.w = 1.0f;
        }
        *reinterpret_cast<float4*>(orow + cbase) = v;
    }
}

extern "C" void kernel_launch(void* const* d_in, const int* in_sizes, int n_in,
                              void* d_out, int out_size, void* d_ws, size_t ws_size,
                              hipStream_t stream) {
    const float* tok = (const float*)d_in[0];
    float* out = (float*)d_out;
    double* invn = (double*)d_ws;                                  // 256 KB
    int* topk = (int*)((char*)d_ws + (size_t)B_ * N_ * sizeof(double)); // 1 MB
    // d_out scratch layout until out_kernel: X2 [0,32MB) | Sim chunk [32,96MB)
    u16* X2 = (u16*)d_out;
    float* Sim = (float*)d_out + (size_t)B_ * N_ * D2 / 2;         // 32 MB offset

    prep_kernel<<<dim3(B_ * N_ / 4), 256, 0, stream>>>(tok, invn, X2);
    for (int c = 0; c < 2; ++c) {                   // 16-batch chunks
        gemm_kernel<<<dim3(8, 8, 16), 256, 0, stream>>>(
            X2 + (size_t)c * 16 * N_ * D2, Sim);
        scan_kernel<<<dim3(16, 16), 256, 0, stream>>>(
            Sim, tok, invn, topk, c * 16);
    }
    out_kernel<<<dim3(B_ * N_ / 4), 256, 0, stream>>>(topk, out);
}